// Round 1
// baseline (840.281 us; speedup 1.0000x reference)
//
#include <hip/hip_runtime.h>
#include <hip/hip_bf16.h>

#define SEQ 4096
#define DM 2048
#define NH 16
#define HD 128

typedef __attribute__((ext_vector_type(4))) float f32x4;
typedef __attribute__((ext_vector_type(8))) short bf16x8;
typedef __attribute__((ext_vector_type(4))) float float4_t;

__device__ __forceinline__ short f2bf(float f) {
  union { float f; unsigned u; } c; c.f = f;
  unsigned u = c.u;
  u += 0x7FFFu + ((u >> 16) & 1u);   // RNE
  return (short)(u >> 16);
}
__device__ __forceinline__ float bf2f(short s) {
  union { unsigned u; float f; } c;
  c.u = ((unsigned)(unsigned short)s) << 16;
  return c.f;
}

__global__ __launch_bounds__(256) void rope_tables_kernel(float* __restrict__ cosT,
                                                          float* __restrict__ sinT) {
  int idx = blockIdx.x * 256 + threadIdx.x;  // SEQ*64
  int s = idx >> 6, j = idx & 63;
  float invf = expf(-(float)j * (9.210340371976184f / 64.0f)); // 10000^(-j/64)
  float ang = (float)s * invf;
  cosT[idx] = cosf(ang);
  sinT[idx] = sinf(ang);
}

// C[M][N] = A[M][K] * B[N][K]^T.  A: bf16 or f32 per template; B: f32 (converted).
template<int A_BF16, int OUT_BF16>
__global__ __launch_bounds__(256) void gemm_bt_kernel(
    const void* __restrict__ Ap, const float* __restrict__ Bp,
    void* __restrict__ Cp, int M, int N, int K) {
  __shared__ short As[128 * 32];
  __shared__ short Bs[128 * 32];
  const int t = threadIdx.x;
  const int lane = t & 63;
  const int wave = t >> 6;
  const int wr = wave >> 1, wc = wave & 1;
  const long Mbase = (long)blockIdx.x * 128;
  const long Nbase = (long)blockIdx.y * 128;
  const int srow = t >> 1;         // 0..127
  const int scol = (t & 1) * 16;   // 0 or 16

  f32x4 acc[4][4] = {};

  for (int k0 = 0; k0 < K; k0 += 32) {
    __syncthreads();
    if (A_BF16) {
      const short* A = (const short*)Ap;
      const short* src = A + (Mbase + srow) * (long)K + k0 + scol;
      *(bf16x8*)&As[srow * 32 + scol]     = *(const bf16x8*)(src);
      *(bf16x8*)&As[srow * 32 + scol + 8] = *(const bf16x8*)(src + 8);
    } else {
      const float* A = (const float*)Ap;
      const float4_t* src = (const float4_t*)(A + (Mbase + srow) * (long)K + k0 + scol);
      short tmp[16];
      #pragma unroll
      for (int i = 0; i < 4; i++) {
        float4_t v = src[i];
        #pragma unroll
        for (int u = 0; u < 4; u++) tmp[i * 4 + u] = f2bf(v[u]);
      }
      *(bf16x8*)&As[srow * 32 + scol]     = *(bf16x8*)&tmp[0];
      *(bf16x8*)&As[srow * 32 + scol + 8] = *(bf16x8*)&tmp[8];
    }
    {
      const float4_t* src = (const float4_t*)(Bp + (Nbase + srow) * (long)K + k0 + scol);
      short tmp[16];
      #pragma unroll
      for (int i = 0; i < 4; i++) {
        float4_t v = src[i];
        #pragma unroll
        for (int u = 0; u < 4; u++) tmp[i * 4 + u] = f2bf(v[u]);
      }
      *(bf16x8*)&Bs[srow * 32 + scol]     = *(bf16x8*)&tmp[0];
      *(bf16x8*)&Bs[srow * 32 + scol + 8] = *(bf16x8*)&tmp[8];
    }
    __syncthreads();

    bf16x8 a[4], b[4];
    #pragma unroll
    for (int m = 0; m < 4; m++)
      a[m] = *(bf16x8*)&As[(wr * 64 + m * 16 + (lane & 15)) * 32 + (lane >> 4) * 8];
    #pragma unroll
    for (int n = 0; n < 4; n++)
      b[n] = *(bf16x8*)&Bs[(wc * 64 + n * 16 + (lane & 15)) * 32 + (lane >> 4) * 8];
    #pragma unroll
    for (int m = 0; m < 4; m++)
      #pragma unroll
      for (int n = 0; n < 4; n++)
        acc[m][n] = __builtin_amdgcn_mfma_f32_16x16x32_bf16(a[m], b[n], acc[m][n], 0, 0, 0);
  }

  #pragma unroll
  for (int m = 0; m < 4; m++)
    #pragma unroll
    for (int n = 0; n < 4; n++)
      #pragma unroll
      for (int j = 0; j < 4; j++) {
        long row = Mbase + wr * 64 + m * 16 + (lane >> 4) * 4 + j;
        long col = Nbase + wc * 64 + n * 16 + (lane & 15);
        float v = acc[m][n][j];
        if (OUT_BF16) ((short*)Cp)[row * N + col] = f2bf(v);
        else          ((float*)Cp)[row * N + col] = v;
      }
}

__global__ __launch_bounds__(256) void rope_apply_kernel(
    short* __restrict__ Q, short* __restrict__ K,
    const float* __restrict__ cosT, const float* __restrict__ sinT) {
  int idx = blockIdx.x * 256 + threadIdx.x;  // SEQ*NH*64
  int j = idx & 63;
  int h = (idx >> 6) & 15;
  int s = idx >> 10;
  long base = (long)s * DM + h * HD;
  float c  = cosT[s * 64 + j];
  float sn = sinT[s * 64 + j];
  float q1 = bf2f(Q[base + j]), q2 = bf2f(Q[base + 64 + j]);
  Q[base + j]      = f2bf(q1 * c - q2 * sn);
  Q[base + 64 + j] = f2bf(q2 * c + q1 * sn);
  float k1 = bf2f(K[base + j]), k2 = bf2f(K[base + 64 + j]);
  K[base + j]      = f2bf(k1 * c - k2 * sn);
  K[base + 64 + j] = f2bf(k2 * c + k1 * sn);
}

// One block per (64-row Q tile, head). 4 waves, wave w owns rows w*16..w*16+15.
__global__ __launch_bounds__(256) void flash_attn_kernel(
    const short* __restrict__ Q, const short* __restrict__ K,
    const short* __restrict__ V, short* __restrict__ O) {
  const int qt = blockIdx.x;
  const int h  = blockIdx.y;
  __shared__ short Qs[64 * 128];
  __shared__ short Ks[64 * 128];
  __shared__ short Vt[128 * 66];   // V transposed: Vt[d][key], stride 66 vs bank conflicts
  __shared__ short Ps[64 * 64];
  const int t = threadIdx.x, lane = t & 63, w = t >> 6;
  const int q0 = qt * 64;

  #pragma unroll
  for (int i = 0; i < 4; i++) {
    int li = t + i * 256;
    int row = li >> 4;
    int col = (li & 15) * 8;
    bf16x8 v = *(const bf16x8*)(Q + (long)(q0 + row) * DM + h * HD + col);
    *(bf16x8*)((char*)Qs + ((row * 256 + col * 2) ^ ((row & 7) << 4))) = v;
  }

  f32x4 oacc[8] = {};
  float mrow[4] = {-1e30f, -1e30f, -1e30f, -1e30f};
  float lrow[4] = {0.f, 0.f, 0.f, 0.f};
  const float scale = 0.08838834764831845f;  // 1/sqrt(128)

  for (int kt = 0; kt <= qt; kt++) {
    __syncthreads();   // protect Ks/Vt from overwrite while prior PV still reading
    #pragma unroll
    for (int i = 0; i < 4; i++) {
      int li = t + i * 256;
      int row = li >> 4;
      int col = (li & 15) * 8;
      long gbase = (long)(kt * 64 + row) * DM + h * HD + col;
      bf16x8 kv = *(const bf16x8*)(K + gbase);
      *(bf16x8*)((char*)Ks + ((row * 256 + col * 2) ^ ((row & 7) << 4))) = kv;
      bf16x8 vv = *(const bf16x8*)(V + gbase);
      #pragma unroll
      for (int u = 0; u < 8; u++) Vt[(col + u) * 66 + row] = vv[u];
    }
    __syncthreads();

    // S = Q K^T  (wave's 16 rows x 64 cols)
    f32x4 sacc[4] = {};
    #pragma unroll
    for (int ks = 0; ks < 4; ks++) {
      const int arow = w * 16 + (lane & 15);
      const int acol = ks * 32 + (lane >> 4) * 8;
      bf16x8 af = *(bf16x8*)((char*)Qs + ((arow * 256 + acol * 2) ^ ((arow & 7) << 4)));
      #pragma unroll
      for (int n = 0; n < 4; n++) {
        const int brow = n * 16 + (lane & 15);
        bf16x8 bfr = *(bf16x8*)((char*)Ks + ((brow * 256 + acol * 2) ^ ((brow & 7) << 4)));
        sacc[n] = __builtin_amdgcn_mfma_f32_16x16x32_bf16(af, bfr, sacc[n], 0, 0, 0);
      }
    }

    // online softmax (fp32)
    float p[4][4];
    float tmax[4];
    const int rbase = q0 + w * 16 + (lane >> 4) * 4;
    const int cbase = kt * 64 + (lane & 15);
    #pragma unroll
    for (int j = 0; j < 4; j++) {
      float mx = -1e30f;
      #pragma unroll
      for (int n = 0; n < 4; n++) {
        float s = sacc[n][j] * scale;
        if (kt == qt && (cbase + n * 16) > (rbase + j)) s = -1e30f;  // causal
        p[n][j] = s;
        mx = fmaxf(mx, s);
      }
      tmax[j] = mx;
    }
    #pragma unroll
    for (int j = 0; j < 4; j++) {
      #pragma unroll
      for (int m = 1; m < 16; m <<= 1)
        tmax[j] = fmaxf(tmax[j], __shfl_xor(tmax[j], m, 64));
      float mnew  = fmaxf(mrow[j], tmax[j]);
      float alpha = __expf(mrow[j] - mnew);
      mrow[j] = mnew;
      float sum = 0.f;
      #pragma unroll
      for (int n = 0; n < 4; n++) {
        float e = __expf(p[n][j] - mnew);
        p[n][j] = e;
        sum += e;
      }
      #pragma unroll
      for (int m = 1; m < 16; m <<= 1)
        sum += __shfl_xor(sum, m, 64);
      lrow[j] = lrow[j] * alpha + sum;
      #pragma unroll
      for (int df = 0; df < 8; df++) oacc[df][j] *= alpha;
    }

    // P -> LDS (bf16) to redistribute into A-fragment layout
    #pragma unroll
    for (int n = 0; n < 4; n++)
      #pragma unroll
      for (int j = 0; j < 4; j++) {
        int prow = w * 16 + (lane >> 4) * 4 + j;
        int pcol = n * 16 + (lane & 15);
        *(short*)((char*)Ps + ((prow * 128 + pcol * 2) ^ ((prow & 7) << 4))) = f2bf(p[n][j]);
      }
    __syncthreads();

    // O += P V
    #pragma unroll
    for (int ks = 0; ks < 2; ks++) {
      const int arow = w * 16 + (lane & 15);
      const int acol = ks * 32 + (lane >> 4) * 8;
      bf16x8 pa = *(bf16x8*)((char*)Ps + ((arow * 128 + acol * 2) ^ ((arow & 7) << 4)));
      #pragma unroll
      for (int df = 0; df < 8; df++) {
        union { int i[4]; bf16x8 v; } ub;
        const int* vp = (const int*)&Vt[(df * 16 + (lane & 15)) * 66 + acol];
        #pragma unroll
        for (int u = 0; u < 4; u++) ub.i[u] = vp[u];
        oacc[df] = __builtin_amdgcn_mfma_f32_16x16x32_bf16(pa, ub.v, oacc[df], 0, 0, 0);
      }
    }
  }

  float inv[4];
  #pragma unroll
  for (int j = 0; j < 4; j++) inv[j] = 1.0f / lrow[j];
  #pragma unroll
  for (int df = 0; df < 8; df++)
    #pragma unroll
    for (int j = 0; j < 4; j++) {
      long row = q0 + w * 16 + (lane >> 4) * 4 + j;
      int col = df * 16 + (lane & 15);
      O[row * DM + h * HD + col] = f2bf(oacc[df][j] * inv[j]);
    }
}

extern "C" void kernel_launch(void* const* d_in, const int* in_sizes, int n_in,
                              void* d_out, int out_size, void* d_ws, size_t ws_size,
                              hipStream_t stream) {
  const float* x  = (const float*)d_in[0];
  const float* wq = (const float*)d_in[1];
  const float* wk = (const float*)d_in[2];
  const float* wv = (const float*)d_in[3];
  const float* wo = (const float*)d_in[4];
  float* out = (float*)d_out;

  short* Qb = (short*)d_ws;
  short* Kb = Qb + (size_t)SEQ * DM;
  short* Vb = Kb + (size_t)SEQ * DM;
  short* Cb = Vb + (size_t)SEQ * DM;
  float* cosT = (float*)(Cb + (size_t)SEQ * DM);
  float* sinT = cosT + SEQ * 64;

  rope_tables_kernel<<<SEQ * 64 / 256, 256, 0, stream>>>(cosT, sinT);

  dim3 g(SEQ / 128, DM / 128);
  gemm_bt_kernel<0, 1><<<g, 256, 0, stream>>>(x, wq, Qb, SEQ, DM, DM);
  gemm_bt_kernel<0, 1><<<g, 256, 0, stream>>>(x, wk, Kb, SEQ, DM, DM);
  gemm_bt_kernel<0, 1><<<g, 256, 0, stream>>>(x, wv, Vb, SEQ, DM, DM);

  rope_apply_kernel<<<SEQ * NH * 64 / 256, 256, 0, stream>>>(Qb, Kb, cosT, sinT);

  flash_attn_kernel<<<dim3(SEQ / 64, NH), 256, 0, stream>>>(Qb, Kb, Vb, Cb);

  gemm_bt_kernel<1, 0><<<g, 256, 0, stream>>>(Cb, wo, out, SEQ, DM, DM);
}

// Round 2
// 375.161 us; speedup vs baseline: 2.2398x; 2.2398x over previous
//
#include <hip/hip_runtime.h>
#include <hip/hip_bf16.h>
#include <stdint.h>

#define SEQ 4096
#define DM 2048
#define NH 16
#define HD 128

typedef __attribute__((ext_vector_type(4))) float f32x4;
typedef __attribute__((ext_vector_type(8))) short bf16x8;
typedef __attribute__((ext_vector_type(4))) float float4_t;
typedef __attribute__((ext_vector_type(4))) short s16x4;

__device__ __forceinline__ short f2bf(float f) {
  union { float f; unsigned u; } c; c.f = f;
  unsigned u = c.u;
  u += 0x7FFFu + ((u >> 16) & 1u);   // RNE
  return (short)(u >> 16);
}
__device__ __forceinline__ float bf2f(short s) {
  union { unsigned u; float f; } c;
  c.u = ((unsigned)(unsigned short)s) << 16;
  return c.f;
}

__device__ __forceinline__ void async16(const void* g, void* l) {
  __builtin_amdgcn_global_load_lds((const __attribute__((address_space(1))) void*)g,
                                   (__attribute__((address_space(3))) void*)l, 16, 0, 0);
}

__global__ __launch_bounds__(256) void rope_tables_kernel(float* __restrict__ cosT,
                                                          float* __restrict__ sinT) {
  int idx = blockIdx.x * 256 + threadIdx.x;  // SEQ*64
  int s = idx >> 6, j = idx & 63;
  float invf = expf(-(float)j * (9.210340371976184f / 64.0f)); // 10000^(-j/64)
  float ang = (float)s * invf;
  cosT[idx] = cosf(ang);
  sinT[idx] = sinf(ang);
}

__global__ __launch_bounds__(256) void f32_to_bf16_kernel(const float* __restrict__ in,
                                                          short* __restrict__ out, int n4) {
  int stride = gridDim.x * 256;
  for (int i = blockIdx.x * 256 + threadIdx.x; i < n4; i += stride) {
    float4_t v = ((const float4_t*)in)[i];
    s16x4 r;
    #pragma unroll
    for (int u = 0; u < 4; u++) r[u] = f2bf(v[u]);
    ((s16x4*)out)[i] = r;
  }
}

// ---------------- fast GEMM: bf16 in, global_load_lds staging, BK=64 -------
// C[M][N] = A[M][K] * B[N][K]^T. OUT_MODE: 0 f32, 1 bf16, 2 bf16 transposed.
template<int OUT_MODE>
__global__ __launch_bounds__(256) void gemm_async_kernel(
    const short* __restrict__ A, const short* __restrict__ B,
    void* __restrict__ Cp, int M, int N, int K) {
  __shared__ short As[128 * 64];
  __shared__ short Bs[128 * 64];
  const int t = threadIdx.x, lane = t & 63, w = t >> 6;
  const int wr = w >> 1, wc = w & 1;
  const size_t Mbase = (size_t)blockIdx.x * 128;
  const size_t Nbase = (size_t)blockIdx.y * 128;
  f32x4 acc[4][4] = {};

  for (int k0 = 0; k0 < K; k0 += 64) {
    __syncthreads();
    // stage A,B: 128 rows x 128B each; swizzled content via pre-swizzled source
    #pragma unroll
    for (int c = 0; c < 4; c++) {
      int ob = w * 4096 + c * 1024;           // uniform per wave
      int o = ob + lane * 16;
      int row = o >> 7;
      int cb = (o & 127) ^ ((row & 7) << 4);
      async16((const char*)A + ((Mbase + row) * (size_t)K + k0) * 2 + cb, (char*)As + ob);
      async16((const char*)B + ((Nbase + row) * (size_t)K + k0) * 2 + cb, (char*)Bs + ob);
    }
    __syncthreads();

    bf16x8 a[2][4], b[2][4];
    #pragma unroll
    for (int ks = 0; ks < 2; ks++) {
      #pragma unroll
      for (int m = 0; m < 4; m++) {
        int row = wr * 64 + m * 16 + (lane & 15);
        int chunk = ks * 64 + (lane >> 4) * 16;
        a[ks][m] = *(const bf16x8*)((const char*)As + row * 128 + (chunk ^ ((row & 7) << 4)));
      }
      #pragma unroll
      for (int n = 0; n < 4; n++) {
        int row = wc * 64 + n * 16 + (lane & 15);
        int chunk = ks * 64 + (lane >> 4) * 16;
        b[ks][n] = *(const bf16x8*)((const char*)Bs + row * 128 + (chunk ^ ((row & 7) << 4)));
      }
    }
    #pragma unroll
    for (int ks = 0; ks < 2; ks++)
      #pragma unroll
      for (int m = 0; m < 4; m++)
        #pragma unroll
        for (int n = 0; n < 4; n++)
          acc[m][n] = __builtin_amdgcn_mfma_f32_16x16x32_bf16(a[ks][m], b[ks][n], acc[m][n], 0, 0, 0);
  }

  #pragma unroll
  for (int m = 0; m < 4; m++)
    #pragma unroll
    for (int n = 0; n < 4; n++)
      #pragma unroll
      for (int j = 0; j < 4; j++) {
        size_t row = Mbase + wr * 64 + m * 16 + (lane >> 4) * 4 + j;
        size_t col = Nbase + wc * 64 + n * 16 + (lane & 15);
        float v = acc[m][n][j];
        if (OUT_MODE == 0)      ((float*)Cp)[row * N + col] = v;
        else if (OUT_MODE == 1) ((short*)Cp)[row * N + col] = f2bf(v);
        else                    ((short*)Cp)[col * (size_t)M + row] = f2bf(v);
      }
}

// ---------------- fallback GEMM (f32 inputs, reg-staged conversion) --------
template<int A_BF16, int OUT_MODE>
__global__ __launch_bounds__(256) void gemm_bt_kernel(
    const void* __restrict__ Ap, const float* __restrict__ Bp,
    void* __restrict__ Cp, int M, int N, int K) {
  __shared__ short As[128 * 32];
  __shared__ short Bs[128 * 32];
  const int t = threadIdx.x;
  const int lane = t & 63;
  const int wave = t >> 6;
  const int wr = wave >> 1, wc = wave & 1;
  const long Mbase = (long)blockIdx.x * 128;
  const long Nbase = (long)blockIdx.y * 128;
  const int srow = t >> 1;
  const int scol = (t & 1) * 16;

  f32x4 acc[4][4] = {};

  for (int k0 = 0; k0 < K; k0 += 32) {
    __syncthreads();
    if (A_BF16) {
      const short* A = (const short*)Ap;
      const short* src = A + (Mbase + srow) * (long)K + k0 + scol;
      *(bf16x8*)&As[srow * 32 + scol]     = *(const bf16x8*)(src);
      *(bf16x8*)&As[srow * 32 + scol + 8] = *(const bf16x8*)(src + 8);
    } else {
      const float* A = (const float*)Ap;
      const float4_t* src = (const float4_t*)(A + (Mbase + srow) * (long)K + k0 + scol);
      short tmp[16];
      #pragma unroll
      for (int i = 0; i < 4; i++) {
        float4_t v = src[i];
        #pragma unroll
        for (int u = 0; u < 4; u++) tmp[i * 4 + u] = f2bf(v[u]);
      }
      *(bf16x8*)&As[srow * 32 + scol]     = *(bf16x8*)&tmp[0];
      *(bf16x8*)&As[srow * 32 + scol + 8] = *(bf16x8*)&tmp[8];
    }
    {
      const float4_t* src = (const float4_t*)(Bp + (Nbase + srow) * (long)K + k0 + scol);
      short tmp[16];
      #pragma unroll
      for (int i = 0; i < 4; i++) {
        float4_t v = src[i];
        #pragma unroll
        for (int u = 0; u < 4; u++) tmp[i * 4 + u] = f2bf(v[u]);
      }
      *(bf16x8*)&Bs[srow * 32 + scol]     = *(bf16x8*)&tmp[0];
      *(bf16x8*)&Bs[srow * 32 + scol + 8] = *(bf16x8*)&tmp[8];
    }
    __syncthreads();

    bf16x8 a[4], b[4];
    #pragma unroll
    for (int m = 0; m < 4; m++)
      a[m] = *(bf16x8*)&As[(wr * 64 + m * 16 + (lane & 15)) * 32 + (lane >> 4) * 8];
    #pragma unroll
    for (int n = 0; n < 4; n++)
      b[n] = *(bf16x8*)&Bs[(wc * 64 + n * 16 + (lane & 15)) * 32 + (lane >> 4) * 8];
    #pragma unroll
    for (int m = 0; m < 4; m++)
      #pragma unroll
      for (int n = 0; n < 4; n++)
        acc[m][n] = __builtin_amdgcn_mfma_f32_16x16x32_bf16(a[m], b[n], acc[m][n], 0, 0, 0);
  }

  #pragma unroll
  for (int m = 0; m < 4; m++)
    #pragma unroll
    for (int n = 0; n < 4; n++)
      #pragma unroll
      for (int j = 0; j < 4; j++) {
        long row = Mbase + wr * 64 + m * 16 + (lane >> 4) * 4 + j;
        long col = Nbase + wc * 64 + n * 16 + (lane & 15);
        float v = acc[m][n][j];
        if (OUT_MODE == 0)      ((float*)Cp)[row * N + col] = v;
        else if (OUT_MODE == 1) ((short*)Cp)[row * N + col] = f2bf(v);
        else                    ((short*)Cp)[col * (long)M + row] = f2bf(v);
      }
}

__global__ __launch_bounds__(256) void rope_apply_kernel(
    short* __restrict__ Q, short* __restrict__ K,
    const float* __restrict__ cosT, const float* __restrict__ sinT) {
  int idx = blockIdx.x * 256 + threadIdx.x;  // SEQ*NH*64
  int j = idx & 63;
  int h = (idx >> 6) & 15;
  int s = idx >> 10;
  long base = (long)s * DM + h * HD;
  float c  = cosT[s * 64 + j];
  float sn = sinT[s * 64 + j];
  float q1 = bf2f(Q[base + j]), q2 = bf2f(Q[base + 64 + j]);
  Q[base + j]      = f2bf(q1 * c - q2 * sn);
  Q[base + 64 + j] = f2bf(q2 * c + q1 * sn);
  float k1 = bf2f(K[base + j]), k2 = bf2f(K[base + 64 + j]);
  K[base + j]      = f2bf(k1 * c - k2 * sn);
  K[base + 64 + j] = f2bf(k2 * c + k1 * sn);
}

// ---------------- flash attention v2: 8 waves, 128x128 tiles, paired -------
// Q,K: [SEQ][DM] bf16 (roped). VT: [DM][SEQ] bf16. O: [SEQ][DM] bf16.
__global__ __launch_bounds__(512) void flash_attn2_kernel(
    const short* __restrict__ Q, const short* __restrict__ K,
    const short* __restrict__ VT, short* __restrict__ O) {
  __shared__ short Ks[128 * 128];  // [key][d]  rows 256B, XOR-swizzled
  __shared__ short Vt[128 * 128];  // [d][key]  rows 256B, XOR-swizzled
  __shared__ short Ps[128 * 128];  // [qrow][key] rows 256B, XOR-swizzled
  const int t = threadIdx.x, lane = t & 63, w = t >> 6;  // w: 0..7
  // XCD-locality remap: heads 2c,2c+1 -> blocks with id%8==c (one XCD's L2)
  const int id = blockIdx.x + 16 * blockIdx.y;   // 0..255
  const int h = (id & 7) * 2 + (id >> 7);
  const int pair = (id >> 3) & 15;               // 0..15
  const float scale = 0.08838834764831845f;      // 1/sqrt(128)

  for (int rep = 0; rep < 2; rep++) {
    const int qt = rep ? (31 - pair) : pair;
    const int q0 = qt * 128;

    // Q fragments in registers: wave w owns rows q0+w*16 .. +15
    bf16x8 qf[4];
    const int qrow = q0 + w * 16 + (lane & 15);
    #pragma unroll
    for (int ks = 0; ks < 4; ks++)
      qf[ks] = *(const bf16x8*)(Q + (size_t)qrow * DM + h * HD + ks * 32 + (lane >> 4) * 8);

    f32x4 oacc[8] = {};
    float mrow[4] = {-1e30f, -1e30f, -1e30f, -1e30f};
    float lrow[4] = {0.f, 0.f, 0.f, 0.f};

    const int nt = qt + 1;
    for (int kt = 0; kt < nt; kt++) {
      __syncthreads();   // all waves done reading previous Ks/Vt
      // stage K tile [128 key][128 d] and VT tile [128 d][128 key]
      #pragma unroll
      for (int i = 0; i < 4; i++) {
        int ob = w * 4096 + i * 1024;   // wave-uniform LDS byte base
        int o = ob + lane * 16;
        int row = o >> 8;
        int cb = (o & 255) ^ ((row & 7) << 4);
        async16((const char*)K + ((size_t)(kt * 128 + row) * DM + h * HD) * 2 + cb,
                (char*)Ks + ob);
        async16((const char*)VT + ((size_t)(h * HD + row) * SEQ + (size_t)kt * 128) * 2 + cb,
                (char*)Vt + ob);
      }
      __syncthreads();   // drains vmcnt

      // S = Q K^T : wave's 16 rows x 128 keys
      f32x4 sacc[8] = {};
      #pragma unroll
      for (int ks = 0; ks < 4; ks++) {
        #pragma unroll
        for (int n = 0; n < 8; n++) {
          int brow = n * 16 + (lane & 15);
          int byte = brow * 256 + (((ks * 32 + (lane >> 4) * 8) * 2) ^ ((brow & 7) << 4));
          bf16x8 b = *(const bf16x8*)((const char*)Ks + byte);
          sacc[n] = __builtin_amdgcn_mfma_f32_16x16x32_bf16(qf[ks], b, sacc[n], 0, 0, 0);
        }
      }

      const bool lastt = (kt == qt);
      const int r0 = q0 + w * 16 + (lane >> 4) * 4;
      const int c0 = kt * 128 + (lane & 15);
      float p[8][4];
      #pragma unroll
      for (int j = 0; j < 4; j++) {
        float mx = -1e30f;
        #pragma unroll
        for (int n = 0; n < 8; n++) {
          float s = sacc[n][j] * scale;
          if (lastt && (c0 + n * 16) > (r0 + j)) s = -1e30f;  // causal
          p[n][j] = s;
          mx = fmaxf(mx, s);
        }
        #pragma unroll
        for (int m = 1; m < 16; m <<= 1)
          mx = fmaxf(mx, __shfl_xor(mx, m, 64));
        float mnew  = fmaxf(mrow[j], mx);
        float alpha = __expf(mrow[j] - mnew);
        mrow[j] = mnew;
        float sum = 0.f;
        #pragma unroll
        for (int n = 0; n < 8; n++) {
          float e = __expf(p[n][j] - mnew);
          p[n][j] = e;
          sum += e;
        }
        #pragma unroll
        for (int m = 1; m < 16; m <<= 1)
          sum += __shfl_xor(sum, m, 64);
        lrow[j] = lrow[j] * alpha + sum;
        #pragma unroll
        for (int df = 0; df < 8; df++) oacc[df][j] *= alpha;
      }

      // P -> Ps (bf16, swizzled); wave-private rows, no barrier needed
      #pragma unroll
      for (int n = 0; n < 8; n++)
        #pragma unroll
        for (int j = 0; j < 4; j++) {
          int prow = w * 16 + (lane >> 4) * 4 + j;
          int pcol = n * 16 + (lane & 15);
          *(short*)((char*)Ps + prow * 256 + ((pcol * 2) ^ ((prow & 7) << 4))) = f2bf(p[n][j]);
        }

      // O += P V : A-frag from Ps, B-frag from Vt
      #pragma unroll
      for (int ks = 0; ks < 4; ks++) {
        int arow = w * 16 + (lane & 15);
        int abyte = arow * 256 + (((ks * 32 + (lane >> 4) * 8) * 2) ^ ((arow & 7) << 4));
        bf16x8 pa = *(const bf16x8*)((const char*)Ps + abyte);
        #pragma unroll
        for (int df = 0; df < 8; df++) {
          int drow = df * 16 + (lane & 15);
          int vbyte = drow * 256 + (((ks * 32 + (lane >> 4) * 8) * 2) ^ ((drow & 7) << 4));
          bf16x8 vb = *(const bf16x8*)((const char*)Vt + vbyte);
          oacc[df] = __builtin_amdgcn_mfma_f32_16x16x32_bf16(pa, vb, oacc[df], 0, 0, 0);
        }
      }
    }

    float inv[4];
    #pragma unroll
    for (int j = 0; j < 4; j++) inv[j] = 1.0f / lrow[j];
    #pragma unroll
    for (int df = 0; df < 8; df++)
      #pragma unroll
      for (int j = 0; j < 4; j++) {
        size_t row = (size_t)q0 + w * 16 + (lane >> 4) * 4 + j;
        int col = df * 16 + (lane & 15);
        O[row * DM + h * HD + col] = f2bf(oacc[df][j] * inv[j]);
      }
  }
}

extern "C" void kernel_launch(void* const* d_in, const int* in_sizes, int n_in,
                              void* d_out, int out_size, void* d_ws, size_t ws_size,
                              hipStream_t stream) {
  const float* x  = (const float*)d_in[0];
  const float* wq = (const float*)d_in[1];
  const float* wk = (const float*)d_in[2];
  const float* wv = (const float*)d_in[3];
  const float* wo = (const float*)d_in[4];
  float* out = (float*)d_out;

  const size_t SQDMs = (size_t)SEQ * DM;   // 8M elements
  short* Qb  = (short*)d_ws;
  short* Kb  = Qb + SQDMs;
  short* VTb = Kb + SQDMs;
  short* Cb  = VTb + SQDMs;

  dim3 g(SEQ / 128, DM / 128);
  const bool fast = ws_size >= (size_t)92 * 1024 * 1024;

  if (fast) {
    short* xbf  = Cb + SQDMs;
    short* wbuf = xbf + SQDMs;
    float* cosT = (float*)(wbuf + (size_t)DM * DM);
    float* sinT = cosT + SEQ * 64;

    rope_tables_kernel<<<SEQ * 64 / 256, 256, 0, stream>>>(cosT, sinT);
    f32_to_bf16_kernel<<<2048, 256, 0, stream>>>(x, xbf, (int)(SQDMs / 4));

    f32_to_bf16_kernel<<<2048, 256, 0, stream>>>(wq, wbuf, DM * DM / 4);
    gemm_async_kernel<1><<<g, 256, 0, stream>>>(xbf, wbuf, Qb, SEQ, DM, DM);
    f32_to_bf16_kernel<<<2048, 256, 0, stream>>>(wk, wbuf, DM * DM / 4);
    gemm_async_kernel<1><<<g, 256, 0, stream>>>(xbf, wbuf, Kb, SEQ, DM, DM);
    f32_to_bf16_kernel<<<2048, 256, 0, stream>>>(wv, wbuf, DM * DM / 4);
    gemm_async_kernel<2><<<g, 256, 0, stream>>>(xbf, wbuf, VTb, SEQ, DM, DM);

    rope_apply_kernel<<<SEQ * NH * 64 / 256, 256, 0, stream>>>(Qb, Kb, cosT, sinT);
    flash_attn2_kernel<<<dim3(16, 16), 512, 0, stream>>>(Qb, Kb, VTb, Cb);

    f32_to_bf16_kernel<<<2048, 256, 0, stream>>>(wo, wbuf, DM * DM / 4);
    gemm_async_kernel<0><<<g, 256, 0, stream>>>(Cb, wbuf, out, SEQ, DM, DM);
  } else {
    float* cosT = (float*)(Cb + SQDMs);
    float* sinT = cosT + SEQ * 64;

    rope_tables_kernel<<<SEQ * 64 / 256, 256, 0, stream>>>(cosT, sinT);
    gemm_bt_kernel<0, 1><<<g, 256, 0, stream>>>(x, wq, Qb, SEQ, DM, DM);
    gemm_bt_kernel<0, 1><<<g, 256, 0, stream>>>(x, wk, Kb, SEQ, DM, DM);
    gemm_bt_kernel<0, 2><<<g, 256, 0, stream>>>(x, wv, VTb, SEQ, DM, DM);
    rope_apply_kernel<<<SEQ * NH * 64 / 256, 256, 0, stream>>>(Qb, Kb, cosT, sinT);
    flash_attn2_kernel<<<dim3(16, 16), 512, 0, stream>>>(Qb, Kb, VTb, Cb);
    gemm_bt_kernel<1, 0><<<g, 256, 0, stream>>>(Cb, wo, out, SEQ, DM, DM);
  }
}